// Round 1
// baseline (400.337 us; speedup 1.0000x reference)
//
#include <hip/hip_runtime.h>

// Batched thin QR (Householder, LAPACK sign convention) for 8192 x (256x16) fp32.
// One 64-lane wave per matrix; lane l owns rows {l, l+64, l+128, l+192} in registers.
// All reductions are in-wave shfl_xor butterflies (bitwise identical across lanes).

constexpr int BATCH = 8192;
constexpr int DROWS = 256;
constexpr int QC    = 16;

__global__ __launch_bounds__(256) void qr_householder_kernel(
    const float* __restrict__ in, float* __restrict__ out)
{
    const int lane = threadIdx.x & 63;
    const int wid  = threadIdx.x >> 6;
    const int b    = blockIdx.x * 4 + wid;

    const float4* __restrict__ A4 = (const float4*)(in  + (size_t)b * (DROWS * QC));
    float4*       __restrict__ O4 = (float4*)      (out + (size_t)b * (DROWS * QC));

    float x[4][QC];   // matrix rows owned by this lane (later reused as Q accumulator)
    float u[4][QC];   // Householder vectors, pre-scaled by sqrt(2/v'v): H = I - u u'

    // ---- load ----
#pragma unroll
    for (int s = 0; s < 4; ++s) {
        const int rr = s * 64 + lane;
#pragma unroll
        for (int q4 = 0; q4 < 4; ++q4) {
            float4 t = A4[rr * 4 + q4];
            x[s][q4*4+0] = t.x; x[s][q4*4+1] = t.y;
            x[s][q4*4+2] = t.z; x[s][q4*4+3] = t.w;
        }
    }

    // ---- Householder factorization ----
#pragma unroll
    for (int j = 0; j < QC; ++j) {
        // column-j norm over rows >= j (only slot 0 can hold rows < j since j < 16 <= 64)
        float x0 = (lane >= j) ? x[0][j] : 0.f;
        float p  = x0*x0 + x[1][j]*x[1][j] + x[2][j]*x[2][j] + x[3][j]*x[3][j];
#pragma unroll
        for (int m = 1; m < 64; m <<= 1) p += __shfl_xor(p, m, 64);
        const float norm2 = p;
        const float xjj   = __shfl(x[0][j], j, 64);          // pivot element (row j)
        const float nrm   = sqrtf(norm2);
        const float alpha = -copysignf(nrm, xjj);            // LAPACK dlarfg sign
        const float vtv   = 2.f * (norm2 - alpha * xjj);     // ||v||^2, v = x - alpha*e_j
        const float sc    = sqrtf(2.f / vtv);                // u = v * sc  =>  H = I - u u'

        u[0][j] = ((lane < j) ? 0.f : (lane == j ? (xjj - alpha) : x[0][j])) * sc;
        u[1][j] = x[1][j] * sc;
        u[2][j] = x[2][j] * sc;
        u[3][j] = x[3][j] * sc;

        // apply H to trailing columns (skip col j itself; R is not needed)
        float w[QC];
#pragma unroll
        for (int k = j + 1; k < QC; ++k) {
            float d = u[0][j]*x[0][k] + u[1][j]*x[1][k] + u[2][j]*x[2][k] + u[3][j]*x[3][k];
#pragma unroll
            for (int m = 1; m < 64; m <<= 1) d += __shfl_xor(d, m, 64);
            w[k] = d;
        }
#pragma unroll
        for (int k = j + 1; k < QC; ++k) {
#pragma unroll
            for (int s = 0; s < 4; ++s) x[s][k] = fmaf(-u[s][j], w[k], x[s][k]);
        }
    }

    // ---- form Q = H_0 H_1 ... H_15 * E  (reuse x as the accumulator Y) ----
#pragma unroll
    for (int k = 0; k < QC; ++k) {
        x[0][k] = (lane == k) ? 1.f : 0.f;
        x[1][k] = 0.f; x[2][k] = 0.f; x[3][k] = 0.f;
    }

#pragma unroll
    for (int j = QC - 1; j >= 0; --j) {
        float w[QC];
#pragma unroll
        for (int k = 0; k < QC; ++k) {
            float d = u[0][j]*x[0][k] + u[1][j]*x[1][k] + u[2][j]*x[2][k] + u[3][j]*x[3][k];
#pragma unroll
            for (int m = 1; m < 64; m <<= 1) d += __shfl_xor(d, m, 64);
            w[k] = d;
        }
#pragma unroll
        for (int k = 0; k < QC; ++k) {
#pragma unroll
            for (int s = 0; s < 4; ++s) x[s][k] = fmaf(-u[s][j], w[k], x[s][k]);
        }
    }

    // ---- store ----
#pragma unroll
    for (int s = 0; s < 4; ++s) {
        const int rr = s * 64 + lane;
#pragma unroll
        for (int q4 = 0; q4 < 4; ++q4) {
            O4[rr * 4 + q4] = make_float4(x[s][q4*4+0], x[s][q4*4+1],
                                          x[s][q4*4+2], x[s][q4*4+3]);
        }
    }
}

extern "C" void kernel_launch(void* const* d_in, const int* in_sizes, int n_in,
                              void* d_out, int out_size, void* d_ws, size_t ws_size,
                              hipStream_t stream) {
    const float* X = (const float*)d_in[0];
    float*       O = (float*)d_out;
    qr_householder_kernel<<<BATCH / 4, 256, 0, stream>>>(X, O);
}